// Round 3
// baseline (224.185 us; speedup 1.0000x reference)
//
#include <hip/hip_runtime.h>
#include <math.h>

#define N_SAMPLES 131072
#define NUM_CLASSES 128
#define NB 256
#define MAX_FPR 0.7f        // 1 - RECALL_THRESHOLD
#define NCHUNK 64           // row chunks in k2 (2048 rows each)

// bin(x; L) = floor((x - L + 14) * 16), clamped to [0,255].
// MUST be the identical expression in k1 (positives) and k2 (all) so the
// positive histogram and the all histogram agree bit-for-bit.
__device__ __forceinline__ int bin_of(float x, float off /* (14-L)*16 */) {
    int b = (int)__fmaf_rn(x, 16.0f, off);
    return min(max(b, 0), NB - 1);
}

// ---------------------------------------------------------------------------
// K1: wave-per-row with 4-row ILP. Each wave owns 16 consecutive rows,
// processed 4 at a time: 4 independent shuffle-reduction chains pipeline the
// ds-op latency. Computes lse[row], CE grand totals, and the positive
// histogram (one global atomic per row).
// ---------------------------------------------------------------------------
__global__ __launch_bounds__(256) void k1_lse(
    const float* __restrict__ pred, const int* __restrict__ tgt,
    float* __restrict__ lse_out, unsigned int* __restrict__ hPos,
    float* __restrict__ ce_accum)
{
    const int lane = threadIdx.x & 63;
    const int wid  = (blockIdx.x * 256 + threadIdx.x) >> 6;   // 0..8191

    float acc_lse = 0.0f, acc_xt = 0.0f, acc_sx = 0.0f;

    #pragma unroll
    for (int it = 0; it < 4; it++) {
        const int r0 = wid * 16 + it * 4;
        const float2 v0 = ((const float2*)(pred + (size_t)(r0 + 0) * 128))[lane];
        const float2 v1 = ((const float2*)(pred + (size_t)(r0 + 1) * 128))[lane];
        const float2 v2 = ((const float2*)(pred + (size_t)(r0 + 2) * 128))[lane];
        const float2 v3 = ((const float2*)(pred + (size_t)(r0 + 3) * 128))[lane];
        const int4 tq = *(const int4*)(tgt + r0);

        float e0 = __expf(v0.x) + __expf(v0.y);
        float e1 = __expf(v1.x) + __expf(v1.y);
        float e2 = __expf(v2.x) + __expf(v2.y);
        float e3 = __expf(v3.x) + __expf(v3.y);
        #pragma unroll
        for (int o = 32; o; o >>= 1) {
            e0 += __shfl_xor(e0, o);
            e1 += __shfl_xor(e1, o);
            e2 += __shfl_xor(e2, o);
            e3 += __shfl_xor(e3, o);
        }
        const float l0 = __logf(e0), l1 = __logf(e1);
        const float l2 = __logf(e2), l3 = __logf(e3);

        if (lane == 0) {
            *(float4*)(lse_out + r0) = make_float4(l0, l1, l2, l3);
            acc_lse += (l0 + l1) + (l2 + l3);
        }
        acc_sx += (v0.x + v0.y) + (v1.x + v1.y) + (v2.x + v2.y) + (v3.x + v3.y);

        // exactly one lane per row holds the target column
        {
            const float2 vs[4] = {v0, v1, v2, v3};
            const int    ts[4] = {tq.x, tq.y, tq.z, tq.w};
            const float  ls[4] = {l0, l1, l2, l3};
            #pragma unroll
            for (int j = 0; j < 4; j++) {
                const int t = ts[j];
                float xt; bool hit = false;
                if (t == 2 * lane)          { xt = vs[j].x; hit = true; }
                else if (t == 2 * lane + 1) { xt = vs[j].y; hit = true; }
                if (hit) {
                    acc_xt += xt;
                    const int b = bin_of(xt, (14.0f - ls[j]) * 16.0f);
                    atomicAdd(&hPos[(t << 8) | b], 1u);
                }
            }
        }
    }

    float part = acc_lse - 0.9f * acc_xt - (0.1f / 128.0f) * acc_sx;
    #pragma unroll
    for (int o = 32; o; o >>= 1) part += __shfl_xor(part, o);
    if (lane == 0) atomicAdd(ce_accum, part);
}

// ---------------------------------------------------------------------------
// K2: all-sample histograms straight from pred (L3-resident re-read).
// Block = (class-group g of 16 classes, 2048-row chunk). float4 per thread
// covers 4 classes of one row; 16 rows per wave-instruction (full 64B lines).
// LDS 16x257 padded histograms; non-atomic partial writeout.
// ---------------------------------------------------------------------------
__global__ __launch_bounds__(256) void k2_hist(
    const float* __restrict__ pred, const float* __restrict__ lse,
    unsigned int* __restrict__ hPart)     // [8*NCHUNK][16][256]
{
    __shared__ unsigned int h[16 * 257];

    const int g     = blockIdx.x & 7;
    const int chunk = blockIdx.x >> 3;    // 0..NCHUNK-1
    const int tid   = threadIdx.x;

    for (int i = tid; i < 16 * 257; i += 256) h[i] = 0u;
    __syncthreads();

    const int lane  = tid & 63;
    const int w     = tid >> 6;           // wave in block
    const int rq    = lane >> 2;          // row within 16
    const int c     = lane & 3;           // col-quad (4 classes)

    #pragma unroll 4
    for (int itr = 0; itr < 32; itr++) {
        const int row = chunk * 2048 + itr * 64 + w * 16 + rq;
        const float4 q = *(const float4*)(pred + (size_t)row * 128 + g * 16 + c * 4);
        const float off = (14.0f - lse[row]) * 16.0f;
        atomicAdd(&h[(c * 4 + 0) * 257 + bin_of(q.x, off)], 1u);
        atomicAdd(&h[(c * 4 + 1) * 257 + bin_of(q.y, off)], 1u);
        atomicAdd(&h[(c * 4 + 2) * 257 + bin_of(q.z, off)], 1u);
        atomicAdd(&h[(c * 4 + 3) * 257 + bin_of(q.w, off)], 1u);
    }
    __syncthreads();

    unsigned int* out = hPart + (size_t)(g * NCHUNK + chunk) * 16 * 256;
    for (int i = tid; i < 16 * 256; i += 256)
        out[i] = h[(i >> 8) * 257 + (i & 255)];
}

// ---------------------------------------------------------------------------
// K4: one wave per class. Sum the NCHUNK partials (coalesced uint4, bins
// held in DESCENDING order per lane), wave scan, clipped trapezoid pAUC.
// ---------------------------------------------------------------------------
__global__ __launch_bounds__(64) void k4_pauc(
    const unsigned int* __restrict__ hPart,
    const unsigned int* __restrict__ hPos,
    float* __restrict__ acc)              // acc[1]=pauc_sum, acc[2]=valid
{
    const int k    = blockIdx.x;
    const int g    = k >> 4;
    const int c    = k & 15;
    const int lane = threadIdx.x;

    // lane owns descending positions lane*4+i  <->  bin 255-(lane*4+i);
    // those 4 bins are the uint4 at ascending index (63-lane), reversed.
    unsigned int a[4] = {0u, 0u, 0u, 0u};
    for (int ch = 0; ch < NCHUNK; ch++) {
        const uint4 q = ((const uint4*)(hPart + ((size_t)(g * NCHUNK + ch) * 16 + c) * 256))[63 - lane];
        a[0] += q.w; a[1] += q.z; a[2] += q.y; a[3] += q.x;
    }
    const uint4 pq = ((const uint4*)(hPos + (k << 8)))[63 - lane];
    const unsigned int p[4] = {pq.w, pq.z, pq.y, pq.x};

    unsigned int la = a[0] + a[1] + a[2] + a[3];
    unsigned int lp = p[0] + p[1] + p[2] + p[3];

    unsigned int ia = la, ip = lp;
    #pragma unroll
    for (int o = 1; o < 64; o <<= 1) {
        const unsigned int ta = __shfl_up(ia, o);
        const unsigned int tp = __shfl_up(ip, o);
        if (lane >= o) { ia += ta; ip += tp; }
    }
    const unsigned int P = __shfl(ip, 63);
    const unsigned int T = __shfl(ia, 63);
    const float Pm = fmaxf((float)P, 1.0f);
    const float Fm = fmaxf((float)(T - P), 1.0f);

    int cumA = (int)(ia - la), cumP = (int)(ip - lp);  // exclusive prefixes
    float contrib = 0.0f;
    #pragma unroll
    for (int i = 0; i < 4; i++) {
        const int f = (int)a[i] - (int)p[i];
        if (f > 0) {
            const float fpr0 = (float)(cumA - cumP) / Fm;
            if (fpr0 < MAX_FPR) {
                const float tpr0 = (float)cumP / Pm;
                const float tpr1 = (float)(cumP + (int)p[i]) / Pm;
                const float fpr1 = (float)(cumA - cumP + f) / Fm;
                if (fpr1 <= MAX_FPR) {
                    contrib += (fpr1 - fpr0) * 0.5f * (tpr0 + tpr1);
                } else {
                    const float tfrac = (MAX_FPR - fpr0) / (fpr1 - fpr0);
                    const float tprc  = tpr0 + tfrac * (tpr1 - tpr0);
                    contrib += (MAX_FPR - fpr0) * 0.5f * (tpr0 + tprc);
                }
            }
        }
        cumA += (int)a[i]; cumP += (int)p[i];
    }

    #pragma unroll
    for (int o = 32; o; o >>= 1) contrib += __shfl_xor(contrib, o);
    if (lane == 0 && P > 0u) {
        atomicAdd(&acc[1], contrib);
        atomicAdd(&acc[2], 1.0f);
    }
}

// ---------------------------------------------------------------------------
// K5: finalize scalar
// ---------------------------------------------------------------------------
__global__ void k5_finalize(const float* __restrict__ acc, float* __restrict__ out)
{
    const float ce    = acc[0] * (1.0f / (float)N_SAMPLES);
    const float valid = fmaxf(acc[2], 1.0f);
    const float pauc  = acc[1] / valid;
    out[0] = 0.5f * ce + 0.5f * (1.0f - pauc * pauc);
}

extern "C" void kernel_launch(void* const* d_in, const int* in_sizes, int n_in,
                              void* d_out, int out_size, void* d_ws, size_t ws_size,
                              hipStream_t stream)
{
    const float* pred = (const float*)d_in[0];
    const int*   tgt  = (const int*)d_in[1];

    char* ws = (char*)d_ws;
    float*        lse   = (float*)ws;                              // 512 KB
    unsigned int* hPos  = (unsigned int*)(ws + 524288);            // 128 KB
    float*        acc   = (float*)(ws + 655360);                   // 16 B
    unsigned int* hPart = (unsigned int*)(ws + 1048576);           // 8 MB

    // zero hPos + acc in one memset (contiguous range)
    hipMemsetAsync(hPos, 0, 131072 + 16, stream);

    k1_lse<<<2048, 256, 0, stream>>>(pred, tgt, lse, hPos, acc);
    k2_hist<<<8 * NCHUNK, 256, 0, stream>>>(pred, lse, hPart);
    k4_pauc<<<NUM_CLASSES, 64, 0, stream>>>(hPart, hPos, acc);
    k5_finalize<<<1, 1, 0, stream>>>(acc, (float*)d_out);
}

// Round 4
// 124.073 us; speedup vs baseline: 1.8069x; 1.8069x over previous
//
#include <hip/hip_runtime.h>
#include <math.h>

#define N_SAMPLES 131072
#define NUM_CLASSES 128
#define NB 256
#define MAX_FPR 0.7f          // 1 - RECALL_THRESHOLD
#define NBLK 256              // fused-kernel grid
#define ROWS_PER_BLK 512      // N_SAMPLES / NBLK
#define HWORDS (NB / 2)       // 128 packed u32 words per class (2 u16 bins each)
#define HPITCH 129            // +1 word pad per class row (bank spread)
#define PART_WORDS (NUM_CLASSES * HWORDS)   // 16384 u32 per block partial

// bin(x; L) = floor((x - L + 14) * 16) clamped to [0,255]. Identical
// expression for the positive and the all histogram (same kernel, same regs).
__device__ __forceinline__ int bin_of(float x, float off /* (14-lse)*16 */) {
    int b = (int)__fmaf_rn(x, 16.0f, off);
    return min(max(b, 0), NB - 1);
}

// ---------------------------------------------------------------------------
// Fused: read pred ONCE. Block = 512 rows + full 128x256 LDS histogram
// (u16 pairs packed in u32; per-block counts <= 512 so halves can't carry).
// 16 lanes per row, 8 cols per lane via two coalesced float4 loads
// (cols j*4 and 64+j*4 -> each wave-load instr covers contiguous 256 floats
// of 4 rows). lse via 4-step 16-lane shuffle reduce. Software-pipelined.
// ---------------------------------------------------------------------------
__global__ __launch_bounds__(1024, 4) void fused_kernel(
    const float* __restrict__ pred, const int* __restrict__ tgt,
    unsigned int* __restrict__ hPos,     // [128][256] global, memset to 0
    unsigned int* __restrict__ part,     // [NBLK][16384] non-atomic partials
    float* __restrict__ ce_accum)
{
    __shared__ unsigned int h32[NUM_CLASSES * HPITCH];   // 66048 B
    __shared__ float wsum[16];

    const int tid  = threadIdx.x;
    const int w    = tid >> 6;        // wave 0..15
    const int lane = tid & 63;
    const int j    = lane & 15;       // lane within row
    const int rs   = lane >> 4;       // row sub-index 0..3

    for (int i = tid; i < NUM_CLASSES * HPITCH; i += 1024) h32[i] = 0u;
    __syncthreads();

    const int rowBase = blockIdx.x * ROWS_PER_BLK + w * 4 + rs;

    float acc_lse = 0.0f, acc_xt = 0.0f, acc_sx = 0.0f;

    // prologue loads (pass 0)
    const float* rp = pred + (size_t)rowBase * 128;
    float4 a0 = *(const float4*)(rp + j * 4);
    float4 a1 = *(const float4*)(rp + 64 + j * 4);
    int    tc = tgt[rowBase];

    #pragma unroll
    for (int p = 0; p < 8; p++) {
        float4 b0, b1; int tn = 0;
        if (p < 7) {   // prefetch next pass while this pass reduces
            const float* rn = pred + (size_t)(rowBase + (p + 1) * 64) * 128;
            b0 = *(const float4*)(rn + j * 4);
            b1 = *(const float4*)(rn + 64 + j * 4);
            tn = tgt[rowBase + (p + 1) * 64];
        }

        float e = __expf(a0.x) + __expf(a0.y) + __expf(a0.z) + __expf(a0.w)
                + __expf(a1.x) + __expf(a1.y) + __expf(a1.z) + __expf(a1.w);
        #pragma unroll
        for (int o = 1; o < 16; o <<= 1) e += __shfl_xor(e, o);
        const float lse = __logf(e);
        const float off = (14.0f - lse) * 16.0f;

        const float xv[8] = {a0.x, a0.y, a0.z, a0.w, a1.x, a1.y, a1.z, a1.w};
        #pragma unroll
        for (int q = 0; q < 8; q++) {
            const int c = (q < 4) ? (j * 4 + q) : (64 + j * 4 + (q - 4));
            const int b = bin_of(xv[q], off);
            atomicAdd(&h32[c * HPITCH + (b >> 1)], (b & 1) ? 65536u : 1u);
        }

        acc_sx += (xv[0] + xv[1] + xv[2] + xv[3])
                + (xv[4] + xv[5] + xv[6] + xv[7]);
        if (j == 0) acc_lse += lse;

        // exactly one of the row's 16 lanes owns the target column
        {
            const int t = tc;
            float xt; bool hit = false;
            if ((t >> 2) == j)                      { xt = xv[t & 3];       hit = true; }
            else if (t >= 64 && ((t - 64) >> 2) == j) { xt = xv[4 + (t & 3)]; hit = true; }
            if (hit) {
                acc_xt += xt;
                atomicAdd(&hPos[(t << 8) | bin_of(xt, off)], 1u);
            }
        }

        a0 = b0; a1 = b1; tc = tn;
    }

    // CE: part = sum(lse) - 0.9*sum(x_t) - (0.1/128)*sum(x)
    float ce = acc_lse - 0.9f * acc_xt - (0.1f / 128.0f) * acc_sx;
    #pragma unroll
    for (int o = 32; o; o >>= 1) ce += __shfl_xor(ce, o);
    if (lane == 0) wsum[w] = ce;
    __syncthreads();

    if (tid == 0) {
        float s = 0.0f;
        #pragma unroll
        for (int i = 0; i < 16; i++) s += wsum[i];
        atomicAdd(ce_accum, s);
    }

    // non-atomic partial writeout: [class][128 packed words], unpadded
    unsigned int* out = part + (size_t)blockIdx.x * PART_WORDS;
    for (int i = tid; i < PART_WORDS; i += 1024)
        out[i] = h32[(i >> 7) * HPITCH + (i & 127)];
}

// ---------------------------------------------------------------------------
// Reducer: one wave per class. Sum NBLK u16-packed partials with lanes
// holding DESCENDING bins (lane owns bins 255-4l..252-4l = uint2 at word
// 126-2l), wave scan, clipped trapezoidal pAUC (same math as rounds 2-3).
// ---------------------------------------------------------------------------
__global__ __launch_bounds__(64) void pauc_reduce(
    const unsigned int* __restrict__ part,
    const unsigned int* __restrict__ hPos,
    float* __restrict__ acc)          // acc[1]=pauc_sum, acc[2]=valid
{
    const int k    = blockIdx.x;
    const int lane = threadIdx.x;

    unsigned int a[4] = {0u, 0u, 0u, 0u};
    const unsigned int* pk = part + k * HWORDS + (126 - 2 * lane);
    #pragma unroll 4
    for (int b = 0; b < NBLK; b++) {
        const uint2 q = *(const uint2*)(pk + (size_t)b * PART_WORDS);
        a[0] += q.y >> 16;  a[1] += q.y & 0xffffu;   // bins 255-4l, 254-4l
        a[2] += q.x >> 16;  a[3] += q.x & 0xffffu;   // bins 253-4l, 252-4l
    }
    const uint4 pq = ((const uint4*)(hPos + (k << 8)))[63 - lane];
    const unsigned int p[4] = {pq.w, pq.z, pq.y, pq.x};

    unsigned int la = a[0] + a[1] + a[2] + a[3];
    unsigned int lp = p[0] + p[1] + p[2] + p[3];

    unsigned int ia = la, ip = lp;
    #pragma unroll
    for (int o = 1; o < 64; o <<= 1) {
        const unsigned int ta = __shfl_up(ia, o);
        const unsigned int tp = __shfl_up(ip, o);
        if (lane >= o) { ia += ta; ip += tp; }
    }
    const unsigned int P = __shfl(ip, 63);
    const unsigned int T = __shfl(ia, 63);
    const float Pm = fmaxf((float)P, 1.0f);
    const float Fm = fmaxf((float)(T - P), 1.0f);

    int cumA = (int)(ia - la), cumP = (int)(ip - lp);   // exclusive prefixes
    float contrib = 0.0f;
    #pragma unroll
    for (int i = 0; i < 4; i++) {
        const int f = (int)a[i] - (int)p[i];
        if (f > 0) {
            const float fpr0 = (float)(cumA - cumP) / Fm;
            if (fpr0 < MAX_FPR) {
                const float tpr0 = (float)cumP / Pm;
                const float tpr1 = (float)(cumP + (int)p[i]) / Pm;
                const float fpr1 = (float)(cumA - cumP + f) / Fm;
                if (fpr1 <= MAX_FPR) {
                    contrib += (fpr1 - fpr0) * 0.5f * (tpr0 + tpr1);
                } else {
                    const float tfrac = (MAX_FPR - fpr0) / (fpr1 - fpr0);
                    const float tprc  = tpr0 + tfrac * (tpr1 - tpr0);
                    contrib += (MAX_FPR - fpr0) * 0.5f * (tpr0 + tprc);
                }
            }
        }
        cumA += (int)a[i]; cumP += (int)p[i];
    }

    #pragma unroll
    for (int o = 32; o; o >>= 1) contrib += __shfl_xor(contrib, o);
    if (lane == 0 && P > 0u) {
        atomicAdd(&acc[1], contrib);
        atomicAdd(&acc[2], 1.0f);
    }
}

__global__ void k5_finalize(const float* __restrict__ acc, float* __restrict__ out)
{
    const float ce    = acc[0] * (1.0f / (float)N_SAMPLES);
    const float valid = fmaxf(acc[2], 1.0f);
    const float pauc  = acc[1] / valid;
    out[0] = 0.5f * ce + 0.5f * (1.0f - pauc * pauc);
}

extern "C" void kernel_launch(void* const* d_in, const int* in_sizes, int n_in,
                              void* d_out, int out_size, void* d_ws, size_t ws_size,
                              hipStream_t stream)
{
    const float* pred = (const float*)d_in[0];
    const int*   tgt  = (const int*)d_in[1];

    char* ws = (char*)d_ws;
    unsigned int* hPos = (unsigned int*)ws;                 // 128 KB
    float*        acc  = (float*)(ws + 131072);             // 16 B (acc[0..2])
    unsigned int* part = (unsigned int*)(ws + 262144);      // 16 MB partials

    hipMemsetAsync(hPos, 0, 131072 + 16, stream);           // hPos + acc

    fused_kernel<<<NBLK, 1024, 0, stream>>>(pred, tgt, hPos, part, acc);
    pauc_reduce<<<NUM_CLASSES, 64, 0, stream>>>(part, hPos, acc);
    k5_finalize<<<1, 1, 0, stream>>>(acc, (float*)d_out);
}

// Round 5
// 116.487 us; speedup vs baseline: 1.9245x; 1.0651x over previous
//
#include <hip/hip_runtime.h>
#include <math.h>

#define N_SAMPLES 131072
#define NUM_CLASSES 128
#define NB 256
#define MAX_FPR 0.7f          // 1 - RECALL_THRESHOLD
#define NBLK 512              // fused-kernel grid (2 blocks/CU)
#define ROWS_PER_BLK 256      // N_SAMPLES / NBLK
#define HWORDS (NB / 2)       // 128 packed u32 words per class (2 u16 bins)
#define HPITCH 129            // +1 word pad per class row (bank spread)
#define PART_WORDS (NUM_CLASSES * HWORDS)   // 16384 u32 per block partial

// bin(x; L) = floor((x - L + 14) * 16) clamped to [0,255]. Identical
// expression for the positive and the all histogram (same kernel, same regs).
__device__ __forceinline__ int bin_of(float x, float off /* (14-lse)*16 */) {
    int b = (int)__fmaf_rn(x, 16.0f, off);
    return min(max(b, 0), NB - 1);
}

// ---------------------------------------------------------------------------
// Fused: read pred ONCE. Block = 256 rows + full 128x256 LDS histogram
// (u16 pairs packed in u32; per-block counts <= 256, no carry). 512 threads
// -> 2 blocks/CU (132 KB LDS). 16 lanes per row, 8 cols per lane via two
// coalesced float4 loads; lse via 4-step 16-lane shuffle; software-pipelined.
// ---------------------------------------------------------------------------
__global__ __launch_bounds__(512, 4) void fused_kernel(
    const float* __restrict__ pred, const int* __restrict__ tgt,
    unsigned int* __restrict__ hPos,     // [128][256] global, memset to 0
    unsigned int* __restrict__ part,     // [NBLK][16384] non-atomic partials
    float* __restrict__ ce_accum)
{
    __shared__ unsigned int h32[NUM_CLASSES * HPITCH];   // 66048 B
    __shared__ float wsum[8];

    const int tid  = threadIdx.x;
    const int w    = tid >> 6;        // wave 0..7
    const int lane = tid & 63;
    const int j    = lane & 15;       // lane within row
    const int rs   = lane >> 4;       // row sub-index 0..3

    for (int i = tid; i < NUM_CLASSES * HPITCH; i += 512) h32[i] = 0u;
    __syncthreads();

    const int rowBase = blockIdx.x * ROWS_PER_BLK + w * 4 + rs;

    float acc_lse = 0.0f, acc_xt = 0.0f, acc_sx = 0.0f;

    // prologue loads (pass 0)
    const float* rp = pred + (size_t)rowBase * 128;
    float4 a0 = *(const float4*)(rp + j * 4);
    float4 a1 = *(const float4*)(rp + 64 + j * 4);
    int    tc = tgt[rowBase];

    #pragma unroll
    for (int p = 0; p < 8; p++) {
        float4 b0, b1; int tn = 0;
        if (p < 7) {   // prefetch next pass while this pass reduces
            const float* rn = pred + (size_t)(rowBase + (p + 1) * 32) * 128;
            b0 = *(const float4*)(rn + j * 4);
            b1 = *(const float4*)(rn + 64 + j * 4);
            tn = tgt[rowBase + (p + 1) * 32];
        }

        float e = __expf(a0.x) + __expf(a0.y) + __expf(a0.z) + __expf(a0.w)
                + __expf(a1.x) + __expf(a1.y) + __expf(a1.z) + __expf(a1.w);
        #pragma unroll
        for (int o = 1; o < 16; o <<= 1) e += __shfl_xor(e, o);
        const float lse = __logf(e);
        const float off = (14.0f - lse) * 16.0f;

        const float xv[8] = {a0.x, a0.y, a0.z, a0.w, a1.x, a1.y, a1.z, a1.w};
        #pragma unroll
        for (int q = 0; q < 8; q++) {
            const int c = (q < 4) ? (j * 4 + q) : (64 + j * 4 + (q - 4));
            const int b = bin_of(xv[q], off);
            atomicAdd(&h32[c * HPITCH + (b >> 1)], (b & 1) ? 65536u : 1u);
        }

        acc_sx += (xv[0] + xv[1] + xv[2] + xv[3])
                + (xv[4] + xv[5] + xv[6] + xv[7]);
        if (j == 0) acc_lse += lse;

        // exactly one of the row's 16 lanes owns the target column
        {
            const int t = tc;
            float xt; bool hit = false;
            if ((t >> 2) == j)                        { xt = xv[t & 3];       hit = true; }
            else if (t >= 64 && ((t - 64) >> 2) == j) { xt = xv[4 + (t & 3)]; hit = true; }
            if (hit) {
                acc_xt += xt;
                atomicAdd(&hPos[(t << 8) | bin_of(xt, off)], 1u);
            }
        }

        a0 = b0; a1 = b1; tc = tn;
    }

    // CE: part = sum(lse) - 0.9*sum(x_t) - (0.1/128)*sum(x)
    float ce = acc_lse - 0.9f * acc_xt - (0.1f / 128.0f) * acc_sx;
    #pragma unroll
    for (int o = 32; o; o >>= 1) ce += __shfl_xor(ce, o);
    if (lane == 0) wsum[w] = ce;
    __syncthreads();

    if (tid == 0) {
        float s = 0.0f;
        #pragma unroll
        for (int i = 0; i < 8; i++) s += wsum[i];
        atomicAdd(ce_accum, s);
    }

    // non-atomic partial writeout: [class][128 packed words], unpadded
    unsigned int* out = part + (size_t)blockIdx.x * PART_WORDS;
    for (int i = tid; i < PART_WORDS; i += 512)
        out[i] = h32[(i >> 7) * HPITCH + (i & 127)];
}

// ---------------------------------------------------------------------------
// Reducer + finalize: one 256-thread block per class. Thread t sums packed
// word (t&127) over half the NBLK partials (coalesced 4B streams, 8-deep
// unroll -> high MLP), LDS merge, wave 0 does the descending-bin scan +
// clipped trapezoidal pAUC. Last-done block (device-scope counter) writes
// the final scalar — no separate finalize launch.
// ---------------------------------------------------------------------------
__global__ __launch_bounds__(256) void pauc_reduce(
    const unsigned int* __restrict__ part,
    const unsigned int* __restrict__ hPos,
    float* __restrict__ acc,          // [0]=ce,[1]=pauc,[2]=valid,[3]=done ctr
    float* __restrict__ out)
{
    __shared__ __align__(16) unsigned int sA[NB];

    const int k    = blockIdx.x;
    const int t    = threadIdx.x;
    const int w    = t & 127;         // packed word within class row
    const int half = t >> 7;          // which half of the block-partials

    unsigned int lo = 0u, hi = 0u;
    const unsigned int* p0 = part + (size_t)(half * (NBLK / 2)) * PART_WORDS
                                  + k * HWORDS + w;
    #pragma unroll 8
    for (int b = 0; b < NBLK / 2; b++) {
        const unsigned int q = p0[(size_t)b * PART_WORDS];
        lo += q & 0xffffu; hi += q >> 16;
    }
    if (half == 0) { sA[2 * w] = lo; sA[2 * w + 1] = hi; }
    __syncthreads();
    if (half == 1) { sA[2 * w] += lo; sA[2 * w + 1] += hi; }
    __syncthreads();

    if (t < 64) {
        const int lane = t;
        // lane owns DESCENDING bins 255-4l..252-4l = uint4 at word 63-l, reversed
        const uint4 q  = ((const uint4*)sA)[63 - lane];
        const unsigned int a[4] = {q.w, q.z, q.y, q.x};
        const uint4 pq = ((const uint4*)(hPos + (k << 8)))[63 - lane];
        const unsigned int p[4] = {pq.w, pq.z, pq.y, pq.x};

        const unsigned int la = a[0] + a[1] + a[2] + a[3];
        const unsigned int lp = p[0] + p[1] + p[2] + p[3];

        unsigned int ia = la, ip = lp;
        #pragma unroll
        for (int o = 1; o < 64; o <<= 1) {
            const unsigned int ta = __shfl_up(ia, o);
            const unsigned int tp = __shfl_up(ip, o);
            if (lane >= o) { ia += ta; ip += tp; }
        }
        const unsigned int P = __shfl(ip, 63);
        const unsigned int T = __shfl(ia, 63);
        const float Pm = fmaxf((float)P, 1.0f);
        const float Fm = fmaxf((float)(T - P), 1.0f);

        int cumA = (int)(ia - la), cumP = (int)(ip - lp);  // exclusive prefixes
        float contrib = 0.0f;
        #pragma unroll
        for (int i = 0; i < 4; i++) {
            const int f = (int)a[i] - (int)p[i];
            if (f > 0) {
                const float fpr0 = (float)(cumA - cumP) / Fm;
                if (fpr0 < MAX_FPR) {
                    const float tpr0 = (float)cumP / Pm;
                    const float tpr1 = (float)(cumP + (int)p[i]) / Pm;
                    const float fpr1 = (float)(cumA - cumP + f) / Fm;
                    if (fpr1 <= MAX_FPR) {
                        contrib += (fpr1 - fpr0) * 0.5f * (tpr0 + tpr1);
                    } else {
                        const float tfrac = (MAX_FPR - fpr0) / (fpr1 - fpr0);
                        const float tprc  = tpr0 + tfrac * (tpr1 - tpr0);
                        contrib += (MAX_FPR - fpr0) * 0.5f * (tpr0 + tprc);
                    }
                }
            }
            cumA += (int)a[i]; cumP += (int)p[i];
        }

        #pragma unroll
        for (int o = 32; o; o >>= 1) contrib += __shfl_xor(contrib, o);

        if (lane == 0) {
            if (P > 0u) {
                atomicAdd(&acc[1], contrib);
                atomicAdd(&acc[2], 1.0f);
            }
            __threadfence();
            const unsigned int done = atomicAdd((unsigned int*)(acc + 3), 1u);
            if (done == NUM_CLASSES - 1) {
                // all blocks' contributions are visible (fence + atomic order)
                const float ces = atomicAdd(&acc[0], 0.0f);
                const float ps  = atomicAdd(&acc[1], 0.0f);
                const float vs  = atomicAdd(&acc[2], 0.0f);
                const float ce   = ces * (1.0f / (float)N_SAMPLES);
                const float pauc = ps / fmaxf(vs, 1.0f);
                out[0] = 0.5f * ce + 0.5f * (1.0f - pauc * pauc);
            }
        }
    }
}

extern "C" void kernel_launch(void* const* d_in, const int* in_sizes, int n_in,
                              void* d_out, int out_size, void* d_ws, size_t ws_size,
                              hipStream_t stream)
{
    const float* pred = (const float*)d_in[0];
    const int*   tgt  = (const int*)d_in[1];

    char* ws = (char*)d_ws;
    unsigned int* hPos = (unsigned int*)ws;                 // 128 KB
    float*        acc  = (float*)(ws + 131072);             // 16 B (acc[0..3])
    unsigned int* part = (unsigned int*)(ws + 262144);      // 32 MB partials

    hipMemsetAsync(hPos, 0, 131072 + 16, stream);           // hPos + acc

    fused_kernel<<<NBLK, 512, 0, stream>>>(pred, tgt, hPos, part, acc);
    pauc_reduce<<<NUM_CLASSES, 256, 0, stream>>>(part, hPos, acc, (float*)d_out);
}